// Round 7
// baseline (228.021 us; speedup 1.0000x reference)
//
#include <hip/hip_runtime.h>
#include <hip/hip_fp16.h>

// Problem constants (from reference)
constexpr int   kNpixHi = 1024;
constexpr int   kNpixLo = 256;
constexpr int   kNv     = 64;
constexpr float kFov    = 12.7875f;   // 0.5*(1024-1)*0.025
constexpr float kPsHi   = 0.025f;     // hi-res pixel scale
constexpr float kDv     = 10.0f;
constexpr float kVel0   = 0.0f;

// Binning geometry: bin = (velocity plane, 128x64 spatial tile)
constexpr int kTileW        = 128;
constexpr int kTileH        = 64;
constexpr int kBinsPerPlane = (kNpixLo / kTileW) * (kNpixLo / kTileH);  // 8
constexpr int kNumBins      = kNv * kBinsPerPlane;                      // 512
constexpr int kBinCapIdeal  = 32768;              // records/bin (expected ~25.2K)
constexpr int kBinCapMin    = 27000;              // below this: fall back
constexpr int kThreadsK1    = 512;                // == kNumBins
constexpr int kWavesK1      = kThreadsK1 / 64;    // 8
constexpr int kSamplesPerBlock = 4096;            // 512 thr x 2 float4
constexpr int kSlice        = 36;                 // fixed LDS records per bin
constexpr int kThreadsK2    = 1024;

// Record: u32 = (f16 value << 16) | pixel_idx (13 bits used)
__device__ __forceinline__ unsigned pack_rec(unsigned idx, float val) {
  return ((unsigned)__half_as_ushort(__float2half(val)) << 16) | idx;
}

// ---------------------------------------------------------------------------
// emit one record: append to the bin's fixed LDS slice; overflow -> direct
// global store with a per-record global cursor slot.
// ---------------------------------------------------------------------------
__device__ __forceinline__ void emit(int bin, unsigned idx, float val,
                                     unsigned int* s_cnt,
                                     unsigned int* lds_rec,
                                     unsigned int* __restrict__ recs,
                                     unsigned int* __restrict__ cursors,
                                     unsigned int binCap) {
  const unsigned rec = pack_rec(idx, val);
  const unsigned off = atomicAdd(&s_cnt[bin], 1u);
  if (off < (unsigned)kSlice) {
    lds_rec[bin * kSlice + off] = rec;
  } else {
    const unsigned slot = atomicAdd(&cursors[bin], 1u);
    if (slot < binCap)
      recs[(size_t)bin * binCap + slot] = rec;
  }
}

__device__ __forceinline__ void emit_pair(int lx, int ly, float wxy,
                                          int iv0, float wv0, float wv1,
                                          unsigned int* s_cnt,
                                          unsigned int* lds_rec,
                                          unsigned int* __restrict__ recs,
                                          unsigned int* __restrict__ cursors,
                                          unsigned int binCap) {
  const int sb   = ((ly >> 6) << 1) | (lx >> 7);     // spatial tile id 0..7
  const int bin0 = (iv0 << 3) | sb;                  // plane iv0
  const unsigned idx = (unsigned)((ly & (kTileH - 1)) * kTileW + (lx & (kTileW - 1)));
  emit(bin0,                 idx, wxy * wv0, s_cnt, lds_rec, recs, cursors, binCap);
  emit(bin0 + kBinsPerPlane, idx, wxy * wv1, s_cnt, lds_rec, recs, cursors, binCap);
}

__device__ __forceinline__ void process_sample(float rr, float dd, float vv, float ff,
                                               unsigned int* s_cnt,
                                               unsigned int* lds_rec,
                                               unsigned int* __restrict__ recs,
                                               unsigned int* __restrict__ cursors,
                                               unsigned int binCap) {
  const float x = (rr + kFov) / kPsHi;
  const float y = (dd + kFov) / kPsHi;
  const float w = (vv - kVel0) / kDv;

  const float xf = floorf(x), yf = floorf(y), wf = floorf(w);
  const int ix0 = (int)xf, iy0 = (int)yf, iv0 = (int)wf;

  if (ix0 < 0 || ix0 >= kNpixHi - 1 ||
      iy0 < 0 || iy0 >= kNpixHi - 1 ||
      iv0 < 0 || iv0 >= kNv - 1)
    return;

  const float fx = x - xf, fy = y - yf, fv = w - wf;

  // fold the 4x4 box-mean (1/16) into the weight
  const float fw  = ff * 0.0625f;
  const float wv0 = fw * (1.0f - fv);
  const float wv1 = fw * fv;

  // low-res pixels of the two hi-res corners per axis; same pixel -> weights
  // merge exactly ((1-f)+f = 1)
  const int lx0 = ix0 >> 2, lx1 = (ix0 + 1) >> 2;
  const int ly0 = iy0 >> 2, ly1 = (iy0 + 1) >> 2;
  const bool tx = (lx1 != lx0), ty = (ly1 != ly0);
  const float wx0 = tx ? (1.0f - fx) : 1.0f;
  const float wy0 = ty ? (1.0f - fy) : 1.0f;

  emit_pair(lx0, ly0, wx0 * wy0, iv0, wv0, wv1, s_cnt, lds_rec, recs, cursors, binCap);
  if (tx)       emit_pair(lx1, ly0, fx * wy0, iv0, wv0, wv1, s_cnt, lds_rec, recs, cursors, binCap);
  if (ty)       emit_pair(lx0, ly1, wx0 * fy, iv0, wv0, wv1, s_cnt, lds_rec, recs, cursors, binCap);
  if (tx && ty) emit_pair(lx1, ly1, fx * fy,  iv0, wv0, wv1, s_cnt, lds_rec, recs, cursors, binCap);
}

// ---------------------------------------------------------------------------
// K1 (single pass): emit into fixed per-bin LDS slices -> reserve global
// ranges -> coalesced per-bin copy-out. Inputs read once.
// ---------------------------------------------------------------------------
__global__ __launch_bounds__(kThreadsK1) void scatter_kernel(
    const float* __restrict__ ra, const float* __restrict__ dec,
    const float* __restrict__ vel, const float* __restrict__ flux,
    unsigned int* __restrict__ recs, unsigned int* __restrict__ cursors,
    int m, unsigned int binCap) {
  __shared__ unsigned int s_cnt[kNumBins];           // 2 KB
  __shared__ unsigned int s_base[kNumBins];          // 2 KB
  __shared__ unsigned int lds_rec[kNumBins * kSlice]; // 72 KB

  const int tid = threadIdx.x;
  const int blockBase = blockIdx.x * kSamplesPerBlock;
  const int sA = blockBase + tid * 4;                    // chunk 0
  const int sB = blockBase + kThreadsK1 * 4 + tid * 4;   // chunk 1

  float4 rA, dA, vA, fA, rB, dB, vB, fB;

#define LOAD4(s0, r4, d4, v4, f4)                                          \
  if ((s0) + 4 <= m) {                                                     \
    r4 = *reinterpret_cast<const float4*>(ra + (s0));                      \
    d4 = *reinterpret_cast<const float4*>(dec + (s0));                     \
    v4 = *reinterpret_cast<const float4*>(vel + (s0));                     \
    f4 = *reinterpret_cast<const float4*>(flux + (s0));                    \
  } else {                                                                 \
    float* rp = &r4.x; float* dp = &d4.x; float* vp = &v4.x; float* fp = &f4.x; \
    _Pragma("unroll")                                                      \
    for (int k = 0; k < 4; ++k) {                                          \
      const int i = (s0) + k;                                              \
      const bool in = (i < m);                                             \
      rp[k] = in ? ra[i]   : 0.0f;                                         \
      dp[k] = in ? dec[i]  : 0.0f;                                         \
      vp[k] = in ? vel[i]  : -1e9f;                                        \
      fp[k] = in ? flux[i] : 0.0f;                                         \
    }                                                                      \
  }

  LOAD4(sA, rA, dA, vA, fA)
  LOAD4(sB, rB, dB, vB, fB)
#undef LOAD4

  // tid == bin index (kThreadsK1 == kNumBins)
  s_cnt[tid] = 0u;
  __syncthreads();

  // single emit pass (geometry computed once)
#pragma unroll
  for (int k = 0; k < 4; ++k)
    process_sample((&rA.x)[k], (&dA.x)[k], (&vA.x)[k], (&fA.x)[k],
                   s_cnt, lds_rec, recs, cursors, binCap);
#pragma unroll
  for (int k = 0; k < 4; ++k)
    process_sample((&rB.x)[k], (&dB.x)[k], (&vB.x)[k], (&fB.x)[k],
                   s_cnt, lds_rec, recs, cursors, binCap);
  __syncthreads();

  // reserve global range for the LDS-resident part of each bin
  {
    const unsigned c0 = s_cnt[tid];
    const unsigned c  = c0 < (unsigned)kSlice ? c0 : (unsigned)kSlice;
    s_base[tid] = c ? atomicAdd(&cursors[tid], c) : 0u;
    s_cnt[tid]  = c;   // clamped count for copy-out
  }
  __syncthreads();

  // coalesced copy-out: one bin per wave at a time (cnt <= 36 -> 1 iter)
  const int wave = tid >> 6, lane = tid & 63;
  for (int b = wave; b < kNumBins; b += kWavesK1) {
    const unsigned cnt  = s_cnt[b];
    const unsigned base = s_base[b];
    unsigned int* __restrict__ seg = recs + (size_t)b * binCap;
    for (unsigned j = lane; j < cnt; j += 64) {
      const unsigned slot = base + j;
      if (slot < binCap) seg[slot] = lds_rec[b * kSlice + j];
    }
  }
}

// ---------------------------------------------------------------------------
// K2: one block per bin -> LDS tile accumulate -> coalesced writeback.
// 1024 threads, 2-deep load pipeline.
// ---------------------------------------------------------------------------
__global__ __launch_bounds__(kThreadsK2) void accum_kernel(
    const unsigned int* __restrict__ recs,
    const unsigned int* __restrict__ cursors,
    float* __restrict__ out, unsigned int binCap) {
  __shared__ float tile[kTileH * kTileW];   // 32 KB
  const int b   = blockIdx.x;
  const int tid = threadIdx.x;

  for (int i = tid; i < kTileH * kTileW; i += kThreadsK2) tile[i] = 0.0f;
  __syncthreads();

  unsigned int cnt = cursors[b];
  if (cnt > binCap) cnt = binCap;
  const unsigned int* __restrict__ rb = recs + (size_t)b * binCap;
  const uint4* __restrict__ rb4 = reinterpret_cast<const uint4*>(rb);

  const unsigned n4 = cnt >> 2;   // uint4 groups
  unsigned i = (unsigned)tid;
  if (i < n4) {
    uint4 cur = rb4[i];
    for (;;) {
      const unsigned nx = i + kThreadsK2;
      const bool have_nx = nx < n4;
      uint4 nq;
      if (have_nx) nq = rb4[nx];      // issue next load before processing cur
#pragma unroll
      for (int j = 0; j < 4; ++j) {
        const unsigned r = (&cur.x)[j];
        atomicAdd(&tile[r & 0xFFFFu],
                  __half2float(__ushort_as_half((unsigned short)(r >> 16))));
      }
      if (!have_nx) break;
      cur = nq; i = nx;
    }
  }
  // remainder
  for (unsigned j = (cnt & ~3u) + tid; j < cnt; j += kThreadsK2) {
    const unsigned r = rb[j];
    atomicAdd(&tile[r & 0xFFFFu],
              __half2float(__ushort_as_half((unsigned short)(r >> 16))));
  }
  __syncthreads();

  // writeback: bins partition the cube, plain stores, fully covers output
  const int p   = b >> 3;
  const int sb  = b & 7;
  const int t_y = sb >> 1;
  const int t_x = sb & 1;
  const size_t outBase = ((size_t)p * kNpixLo + (size_t)t_y * kTileH) * kNpixLo
                       + (size_t)t_x * kTileW;
  for (int i2 = tid; i2 < (kTileH * kTileW) / 4; i2 += kThreadsK2) {
    const int wrd = i2 * 4;
    const int ry = wrd >> 7;          // /128
    const int rx = wrd & (kTileW - 1);
    *reinterpret_cast<float4*>(&out[outBase + (size_t)ry * kNpixLo + rx]) =
        *reinterpret_cast<const float4*>(&tile[wrd]);
  }
}

// ---------------------------------------------------------------------------
// Fallback: direct device-atomic kernel if workspace is too small
// ---------------------------------------------------------------------------
__device__ __forceinline__ void splat2(float* __restrict__ out, int planeBase,
                                       int lx, int ly, float wxy,
                                       float wv0, float wv1) {
  const int s = ly * kNpixLo + lx;
  atomicAdd(out + planeBase + s, wxy * wv0);
  atomicAdd(out + planeBase + kNpixLo * kNpixLo + s, wxy * wv1);
}

__global__ __launch_bounds__(256) void cloud_raster_direct(
    const float* __restrict__ ra, const float* __restrict__ dec,
    const float* __restrict__ vel, const float* __restrict__ flux,
    float* __restrict__ out, int m) {
  const int t    = blockIdx.x * blockDim.x + threadIdx.x;
  const int base = t * 4;
  if (base >= m) return;
  float4 r4, d4, v4, f4;
  if (base + 4 <= m) {
    r4 = *reinterpret_cast<const float4*>(ra + base);
    d4 = *reinterpret_cast<const float4*>(dec + base);
    v4 = *reinterpret_cast<const float4*>(vel + base);
    f4 = *reinterpret_cast<const float4*>(flux + base);
  } else {
    float* rp = &r4.x; float* dp = &d4.x; float* vp = &v4.x; float* fp = &f4.x;
#pragma unroll
    for (int k = 0; k < 4; ++k) {
      const int i = base + k;
      rp[k] = (i < m) ? ra[i]   : 0.0f;
      dp[k] = (i < m) ? dec[i]  : 0.0f;
      vp[k] = (i < m) ? vel[i]  : -1e9f;
      fp[k] = (i < m) ? flux[i] : 0.0f;
    }
  }
#pragma unroll
  for (int k = 0; k < 4; ++k) {
    const float rr = (&r4.x)[k], dd = (&d4.x)[k], vv = (&v4.x)[k], ff = (&f4.x)[k];
    const float x = (rr + kFov) / kPsHi;
    const float y = (dd + kFov) / kPsHi;
    const float w = (vv - kVel0) / kDv;
    const float xf = floorf(x), yf = floorf(y), wf = floorf(w);
    const int ix0 = (int)xf, iy0 = (int)yf, iv0 = (int)wf;
    if (ix0 < 0 || ix0 >= kNpixHi - 1 || iy0 < 0 || iy0 >= kNpixHi - 1 ||
        iv0 < 0 || iv0 >= kNv - 1)
      continue;
    const float fx = x - xf, fy = y - yf, fv = w - wf;
    const float fw  = ff * 0.0625f;
    const float wv0 = fw * (1.0f - fv);
    const float wv1 = fw * fv;
    const int lx0 = ix0 >> 2, lx1 = (ix0 + 1) >> 2;
    const int ly0 = iy0 >> 2, ly1 = (iy0 + 1) >> 2;
    const bool tx = (lx1 != lx0), ty = (ly1 != ly0);
    const float wx0 = tx ? (1.0f - fx) : 1.0f;
    const float wy0 = ty ? (1.0f - fy) : 1.0f;
    const int pb = iv0 * (kNpixLo * kNpixLo);
    splat2(out, pb, lx0, ly0, wx0 * wy0, wv0, wv1);
    if (tx)       splat2(out, pb, lx1, ly0, fx  * wy0, wv0, wv1);
    if (ty)       splat2(out, pb, lx0, ly1, wx0 * fy,  wv0, wv1);
    if (tx && ty) splat2(out, pb, lx1, ly1, fx  * fy,  wv0, wv1);
  }
}

// ---------------------------------------------------------------------------

extern "C" void kernel_launch(void* const* d_in, const int* in_sizes, int n_in,
                              void* d_out, int out_size, void* d_ws, size_t ws_size,
                              hipStream_t stream) {
  (void)n_in;
  const float* ra   = (const float*)d_in[0];
  const float* dec  = (const float*)d_in[1];
  const float* vel  = (const float*)d_in[2];
  const float* flux = (const float*)d_in[3];
  float* out = (float*)d_out;
  const int m = in_sizes[0];

  // adaptive per-bin capacity from available workspace (4B records)
  constexpr size_t kCursorBytes = 4096;   // >= kNumBins*4
  unsigned int binCap = 0;
  if (ws_size > kCursorBytes) {
    const size_t avail = (ws_size - kCursorBytes) / ((size_t)kNumBins * 4);
    binCap = (unsigned int)(avail < (size_t)kBinCapIdeal ? avail : (size_t)kBinCapIdeal);
    binCap &= ~3u;   // keep 16B alignment for uint4 reads in K2
  }

  if (binCap >= kBinCapMin) {
    unsigned int* cursors = (unsigned int*)d_ws;
    unsigned int* recs = (unsigned int*)((char*)d_ws + kCursorBytes);
    hipMemsetAsync(d_ws, 0, kCursorBytes, stream);   // zero bin cursors each call
    const int blocks = (m + kSamplesPerBlock - 1) / kSamplesPerBlock;
    scatter_kernel<<<blocks, kThreadsK1, 0, stream>>>(ra, dec, vel, flux, recs, cursors, m, binCap);
    accum_kernel<<<kNumBins, kThreadsK2, 0, stream>>>(recs, cursors, out, binCap);
  } else {
    // workspace too small: direct-atomic fallback
    hipMemsetAsync(d_out, 0, (size_t)out_size * sizeof(float), stream);
    const int threads = 256;
    const int nThreads = (m + 3) / 4;
    const int blocks = (nThreads + threads - 1) / threads;
    cloud_raster_direct<<<blocks, threads, 0, stream>>>(ra, dec, vel, flux, out, m);
  }
}

// Round 8
// 142.401 us; speedup vs baseline: 1.6013x; 1.6013x over previous
//
#include <hip/hip_runtime.h>
#include <hip/hip_fp16.h>

// Problem constants (from reference)
constexpr int   kNpixHi = 1024;
constexpr int   kNpixLo = 256;
constexpr int   kNv     = 64;
constexpr float kFov    = 12.7875f;   // 0.5*(1024-1)*0.025
constexpr float kPsHi   = 0.025f;     // hi-res pixel scale
constexpr float kDv     = 10.0f;
constexpr float kVel0   = 0.0f;

// Binning geometry: bin = (velocity plane, 128x64 spatial tile)
constexpr int kTileW        = 128;
constexpr int kTileH        = 64;
constexpr int kBinsPerPlane = (kNpixLo / kTileW) * (kNpixLo / kTileH);  // 8
constexpr int kNumBins      = kNv * kBinsPerPlane;                      // 512
constexpr int kBinCapIdeal  = 32768;              // records/bin (expected ~25.2K)
constexpr int kBinCapMin    = 27000;              // below this: fall back
constexpr int kThreadsK1    = 512;                // == kNumBins (scan uses this)
constexpr int kWavesK1      = kThreadsK1 / 64;    // 8
constexpr int kSamplesPerBlock = 4096;            // 512 thr x 2 float4
constexpr int kLdsRecCap    = 16384;              // LDS staging records (64 KB)
constexpr int kThreadsK2    = 1024;

// Record: u32 = (f16 value << 16) | pixel_idx (13 bits used)
__device__ __forceinline__ unsigned pack_rec(unsigned idx, float val) {
  return ((unsigned)__half_as_ushort(__float2half(val)) << 16) | idx;
}

enum EmitMode { kCount, kLds, kDirect };

// ---------------------------------------------------------------------------
// emit one record (count / LDS-compact / direct-global)
// ---------------------------------------------------------------------------
template <EmitMode MODE>
__device__ __forceinline__ void emit(int bin, unsigned idx, float val,
                                     unsigned int* s_cnt,
                                     const unsigned int* s_base,
                                     const unsigned int* s_ofs,
                                     unsigned int* lds_rec,
                                     unsigned int* __restrict__ recs,
                                     unsigned int binCap) {
  if (MODE == kCount) {
    atomicAdd(&s_cnt[bin], 1u);
    return;
  }
  const unsigned off = atomicAdd(&s_cnt[bin], 1u);
  if (MODE == kLds) {
    lds_rec[s_ofs[bin] + off] = pack_rec(idx, val);
  } else {
    const unsigned slot = s_base[bin] + off;
    if (slot < binCap)
      recs[(size_t)bin * binCap + slot] = pack_rec(idx, val);
  }
}

template <EmitMode MODE>
__device__ __forceinline__ void emit_pair(int lx, int ly, float wxy,
                                          int iv0, float wv0, float wv1,
                                          unsigned int* s_cnt,
                                          const unsigned int* s_base,
                                          const unsigned int* s_ofs,
                                          unsigned int* lds_rec,
                                          unsigned int* __restrict__ recs,
                                          unsigned int binCap) {
  const int sb   = ((ly >> 6) << 1) | (lx >> 7);     // spatial tile id 0..7
  const int bin0 = (iv0 << 3) | sb;                  // plane iv0
  const unsigned idx = (unsigned)((ly & (kTileH - 1)) * kTileW + (lx & (kTileW - 1)));
  emit<MODE>(bin0,                 idx, wxy * wv0, s_cnt, s_base, s_ofs, lds_rec, recs, binCap);
  emit<MODE>(bin0 + kBinsPerPlane, idx, wxy * wv1, s_cnt, s_base, s_ofs, lds_rec, recs, binCap);
}

template <EmitMode MODE>
__device__ __forceinline__ void process_sample(float rr, float dd, float vv, float ff,
                                               unsigned int* s_cnt,
                                               const unsigned int* s_base,
                                               const unsigned int* s_ofs,
                                               unsigned int* lds_rec,
                                               unsigned int* __restrict__ recs,
                                               unsigned int binCap) {
  const float x = (rr + kFov) / kPsHi;
  const float y = (dd + kFov) / kPsHi;
  const float w = (vv - kVel0) / kDv;

  const float xf = floorf(x), yf = floorf(y), wf = floorf(w);
  const int ix0 = (int)xf, iy0 = (int)yf, iv0 = (int)wf;

  if (ix0 < 0 || ix0 >= kNpixHi - 1 ||
      iy0 < 0 || iy0 >= kNpixHi - 1 ||
      iv0 < 0 || iv0 >= kNv - 1)
    return;

  const float fx = x - xf, fy = y - yf, fv = w - wf;

  // fold the 4x4 box-mean (1/16) into the weight
  const float fw  = ff * 0.0625f;
  const float wv0 = fw * (1.0f - fv);
  const float wv1 = fw * fv;

  // low-res pixels of the two hi-res corners per axis; same pixel -> weights
  // merge exactly ((1-f)+f = 1)
  const int lx0 = ix0 >> 2, lx1 = (ix0 + 1) >> 2;
  const int ly0 = iy0 >> 2, ly1 = (iy0 + 1) >> 2;
  const bool tx = (lx1 != lx0), ty = (ly1 != ly0);
  const float wx0 = tx ? (1.0f - fx) : 1.0f;
  const float wy0 = ty ? (1.0f - fy) : 1.0f;

  emit_pair<MODE>(lx0, ly0, wx0 * wy0, iv0, wv0, wv1, s_cnt, s_base, s_ofs, lds_rec, recs, binCap);
  if (tx)       emit_pair<MODE>(lx1, ly0, fx * wy0, iv0, wv0, wv1, s_cnt, s_base, s_ofs, lds_rec, recs, binCap);
  if (ty)       emit_pair<MODE>(lx0, ly1, wx0 * fy, iv0, wv0, wv1, s_cnt, s_base, s_ofs, lds_rec, recs, binCap);
  if (tx && ty) emit_pair<MODE>(lx1, ly1, fx * fy,  iv0, wv0, wv1, s_cnt, s_base, s_ofs, lds_rec, recs, binCap);
}

// ---------------------------------------------------------------------------
// K1 (r6-proven): count -> block prefix-scan + global reserve -> LDS-compact
// records -> coalesced per-bin copy-out. Inputs read ONCE into registers.
// ---------------------------------------------------------------------------
__global__ __launch_bounds__(kThreadsK1) void scatter_kernel(
    const float* __restrict__ ra, const float* __restrict__ dec,
    const float* __restrict__ vel, const float* __restrict__ flux,
    unsigned int* __restrict__ recs, unsigned int* __restrict__ cursors,
    int m, unsigned int binCap) {
  __shared__ unsigned int s_cnt[kNumBins];
  __shared__ unsigned int s_base[kNumBins];
  __shared__ unsigned int s_ofs[kNumBins];
  __shared__ unsigned int s_wbase[kWavesK1];
  __shared__ unsigned int s_wsum[kWavesK1];
  __shared__ unsigned int s_total;
  __shared__ unsigned int lds_rec[kLdsRecCap];   // 64 KB staging

  const int tid = threadIdx.x;
  const int blockBase = blockIdx.x * kSamplesPerBlock;
  const int sA = blockBase + tid * 4;                    // chunk 0
  const int sB = blockBase + kThreadsK1 * 4 + tid * 4;   // chunk 1

  float4 rA, dA, vA, fA, rB, dB, vB, fB;

#define LOAD4(s0, r4, d4, v4, f4)                                          \
  if ((s0) + 4 <= m) {                                                     \
    r4 = *reinterpret_cast<const float4*>(ra + (s0));                      \
    d4 = *reinterpret_cast<const float4*>(dec + (s0));                     \
    v4 = *reinterpret_cast<const float4*>(vel + (s0));                     \
    f4 = *reinterpret_cast<const float4*>(flux + (s0));                    \
  } else {                                                                 \
    float* rp = &r4.x; float* dp = &d4.x; float* vp = &v4.x; float* fp = &f4.x; \
    _Pragma("unroll")                                                      \
    for (int k = 0; k < 4; ++k) {                                          \
      const int i = (s0) + k;                                              \
      const bool in = (i < m);                                             \
      rp[k] = in ? ra[i]   : 0.0f;                                         \
      dp[k] = in ? dec[i]  : 0.0f;                                         \
      vp[k] = in ? vel[i]  : -1e9f;                                        \
      fp[k] = in ? flux[i] : 0.0f;                                         \
    }                                                                      \
  }

  LOAD4(sA, rA, dA, vA, fA)
  LOAD4(sB, rB, dB, vB, fB)
#undef LOAD4

  // tid == bin index (kThreadsK1 == kNumBins)
  s_cnt[tid] = 0u;
  __syncthreads();

  // phase 1: count records per bin
#pragma unroll
  for (int k = 0; k < 4; ++k)
    process_sample<kCount>((&rA.x)[k], (&dA.x)[k], (&vA.x)[k], (&fA.x)[k],
                           s_cnt, s_base, s_ofs, lds_rec, recs, binCap);
#pragma unroll
  for (int k = 0; k < 4; ++k)
    process_sample<kCount>((&rB.x)[k], (&dB.x)[k], (&vB.x)[k], (&fB.x)[k],
                           s_cnt, s_base, s_ofs, lds_rec, recs, binCap);
  __syncthreads();

  // block-wide exclusive scan of s_cnt (512 entries, one per thread)
  const unsigned c = s_cnt[tid];
  unsigned v = c;
#pragma unroll
  for (int d = 1; d < 64; d <<= 1) {
    const unsigned n = __shfl_up(v, d, 64);
    if ((tid & 63) >= d) v += n;
  }
  if ((tid & 63) == 63) s_wsum[tid >> 6] = v;
  __syncthreads();
  if (tid == 0) {
    unsigned acc = 0;
#pragma unroll
    for (int i = 0; i < kWavesK1; ++i) { s_wbase[i] = acc; acc += s_wsum[i]; }
    s_total = acc;
  }
  __syncthreads();
  s_ofs[tid]  = s_wbase[tid >> 6] + v - c;                 // exclusive prefix
  s_base[tid] = c ? atomicAdd(&cursors[tid], c) : 0u;      // global reserve
  s_cnt[tid]  = 0u;                                        // reset cursors
  __syncthreads();

  const bool ldsPath = (s_total <= (unsigned)kLdsRecCap);

  if (ldsPath) {
    // phase 2a: compact records into LDS
#pragma unroll
    for (int k = 0; k < 4; ++k)
      process_sample<kLds>((&rA.x)[k], (&dA.x)[k], (&vA.x)[k], (&fA.x)[k],
                           s_cnt, s_base, s_ofs, lds_rec, recs, binCap);
#pragma unroll
    for (int k = 0; k < 4; ++k)
      process_sample<kLds>((&rB.x)[k], (&dB.x)[k], (&vB.x)[k], (&fB.x)[k],
                           s_cnt, s_base, s_ofs, lds_rec, recs, binCap);
    __syncthreads();

    // phase 2b: coalesced copy-out, one bin at a time per wave
    const int wave = tid >> 6, lane = tid & 63;
    for (int b = wave; b < kNumBins; b += kWavesK1) {
      const unsigned cnt  = s_cnt[b];
      const unsigned ofs  = s_ofs[b];
      const unsigned base = s_base[b];
      unsigned int* __restrict__ seg = recs + (size_t)b * binCap;
      for (unsigned j = lane; j < cnt; j += 64) {
        const unsigned slot = base + j;
        if (slot < binCap) seg[slot] = lds_rec[ofs + j];
      }
    }
  } else {
    // overflow fallback (deterministic per-block): direct scattered stores
#pragma unroll
    for (int k = 0; k < 4; ++k)
      process_sample<kDirect>((&rA.x)[k], (&dA.x)[k], (&vA.x)[k], (&fA.x)[k],
                              s_cnt, s_base, s_ofs, lds_rec, recs, binCap);
#pragma unroll
    for (int k = 0; k < 4; ++k)
      process_sample<kDirect>((&rB.x)[k], (&dB.x)[k], (&vB.x)[k], (&fB.x)[k],
                              s_cnt, s_base, s_ofs, lds_rec, recs, binCap);
  }
}

// ---------------------------------------------------------------------------
// K2: one block per bin -> LDS tile accumulate -> coalesced writeback.
// 1024 threads (2 blocks/CU = full wave occupancy) + depth-2 load pipeline.
// ---------------------------------------------------------------------------
__global__ __launch_bounds__(kThreadsK2) void accum_kernel(
    const unsigned int* __restrict__ recs,
    const unsigned int* __restrict__ cursors,
    float* __restrict__ out, unsigned int binCap) {
  __shared__ float tile[kTileH * kTileW];   // 32 KB
  const int b   = blockIdx.x;
  const int tid = threadIdx.x;

  for (int i = tid; i < kTileH * kTileW; i += kThreadsK2) tile[i] = 0.0f;
  __syncthreads();

  unsigned int cnt = cursors[b];
  if (cnt > binCap) cnt = binCap;
  const unsigned int* __restrict__ rb = recs + (size_t)b * binCap;
  const uint4* __restrict__ rb4 = reinterpret_cast<const uint4*>(rb);

  const unsigned n4 = cnt >> 2;   // uint4 groups
  {
    unsigned i = (unsigned)tid;
    uint4 cur, nxt;
    bool haveCur = i < n4;
    if (haveCur) cur = rb4[i];
    unsigned in1 = i + kThreadsK2;
    bool haveNxt = in1 < n4;
    if (haveNxt) nxt = rb4[in1];
    while (haveCur) {
      // prefetch 2 ahead before touching cur
      const unsigned i2 = i + 2 * kThreadsK2;
      const bool have2 = i2 < n4;
      uint4 q2;
      if (have2) q2 = rb4[i2];
#pragma unroll
      for (int j = 0; j < 4; ++j) {
        const unsigned r = (&cur.x)[j];
        atomicAdd(&tile[r & 0xFFFFu],
                  __half2float(__ushort_as_half((unsigned short)(r >> 16))));
      }
      cur = nxt; haveCur = haveNxt;
      nxt = q2;  haveNxt = have2;
      i += kThreadsK2;
    }
  }
  // remainder
  for (unsigned j = (cnt & ~3u) + tid; j < cnt; j += kThreadsK2) {
    const unsigned r = rb[j];
    atomicAdd(&tile[r & 0xFFFFu],
              __half2float(__ushort_as_half((unsigned short)(r >> 16))));
  }
  __syncthreads();

  // writeback: bins partition the cube, plain stores, fully covers output
  const int p   = b >> 3;
  const int sb  = b & 7;
  const int t_y = sb >> 1;
  const int t_x = sb & 1;
  const size_t outBase = ((size_t)p * kNpixLo + (size_t)t_y * kTileH) * kNpixLo
                       + (size_t)t_x * kTileW;
  for (int i2 = tid; i2 < (kTileH * kTileW) / 4; i2 += kThreadsK2) {
    const int wrd = i2 * 4;
    const int ry = wrd >> 7;          // /128
    const int rx = wrd & (kTileW - 1);
    *reinterpret_cast<float4*>(&out[outBase + (size_t)ry * kNpixLo + rx]) =
        *reinterpret_cast<const float4*>(&tile[wrd]);
  }
}

// ---------------------------------------------------------------------------
// Fallback: direct device-atomic kernel if workspace is too small
// ---------------------------------------------------------------------------
__device__ __forceinline__ void splat2(float* __restrict__ out, int planeBase,
                                       int lx, int ly, float wxy,
                                       float wv0, float wv1) {
  const int s = ly * kNpixLo + lx;
  atomicAdd(out + planeBase + s, wxy * wv0);
  atomicAdd(out + planeBase + kNpixLo * kNpixLo + s, wxy * wv1);
}

__global__ __launch_bounds__(256) void cloud_raster_direct(
    const float* __restrict__ ra, const float* __restrict__ dec,
    const float* __restrict__ vel, const float* __restrict__ flux,
    float* __restrict__ out, int m) {
  const int t    = blockIdx.x * blockDim.x + threadIdx.x;
  const int base = t * 4;
  if (base >= m) return;
  float4 r4, d4, v4, f4;
  if (base + 4 <= m) {
    r4 = *reinterpret_cast<const float4*>(ra + base);
    d4 = *reinterpret_cast<const float4*>(dec + base);
    v4 = *reinterpret_cast<const float4*>(vel + base);
    f4 = *reinterpret_cast<const float4*>(flux + base);
  } else {
    float* rp = &r4.x; float* dp = &d4.x; float* vp = &v4.x; float* fp = &f4.x;
#pragma unroll
    for (int k = 0; k < 4; ++k) {
      const int i = base + k;
      rp[k] = (i < m) ? ra[i]   : 0.0f;
      dp[k] = (i < m) ? dec[i]  : 0.0f;
      vp[k] = (i < m) ? vel[i]  : -1e9f;
      fp[k] = (i < m) ? flux[i] : 0.0f;
    }
  }
#pragma unroll
  for (int k = 0; k < 4; ++k) {
    const float rr = (&r4.x)[k], dd = (&d4.x)[k], vv = (&v4.x)[k], ff = (&f4.x)[k];
    const float x = (rr + kFov) / kPsHi;
    const float y = (dd + kFov) / kPsHi;
    const float w = (vv - kVel0) / kDv;
    const float xf = floorf(x), yf = floorf(y), wf = floorf(w);
    const int ix0 = (int)xf, iy0 = (int)yf, iv0 = (int)wf;
    if (ix0 < 0 || ix0 >= kNpixHi - 1 || iy0 < 0 || iy0 >= kNpixHi - 1 ||
        iv0 < 0 || iv0 >= kNv - 1)
      continue;
    const float fx = x - xf, fy = y - yf, fv = w - wf;
    const float fw  = ff * 0.0625f;
    const float wv0 = fw * (1.0f - fv);
    const float wv1 = fw * fv;
    const int lx0 = ix0 >> 2, lx1 = (ix0 + 1) >> 2;
    const int ly0 = iy0 >> 2, ly1 = (iy0 + 1) >> 2;
    const bool tx = (lx1 != lx0), ty = (ly1 != ly0);
    const float wx0 = tx ? (1.0f - fx) : 1.0f;
    const float wy0 = ty ? (1.0f - fy) : 1.0f;
    const int pb = iv0 * (kNpixLo * kNpixLo);
    splat2(out, pb, lx0, ly0, wx0 * wy0, wv0, wv1);
    if (tx)       splat2(out, pb, lx1, ly0, fx  * wy0, wv0, wv1);
    if (ty)       splat2(out, pb, lx0, ly1, wx0 * fy,  wv0, wv1);
    if (tx && ty) splat2(out, pb, lx1, ly1, fx  * fy,  wv0, wv1);
  }
}

// ---------------------------------------------------------------------------

extern "C" void kernel_launch(void* const* d_in, const int* in_sizes, int n_in,
                              void* d_out, int out_size, void* d_ws, size_t ws_size,
                              hipStream_t stream) {
  (void)n_in;
  const float* ra   = (const float*)d_in[0];
  const float* dec  = (const float*)d_in[1];
  const float* vel  = (const float*)d_in[2];
  const float* flux = (const float*)d_in[3];
  float* out = (float*)d_out;
  const int m = in_sizes[0];

  // adaptive per-bin capacity from available workspace (4B records)
  constexpr size_t kCursorBytes = 4096;   // >= kNumBins*4
  unsigned int binCap = 0;
  if (ws_size > kCursorBytes) {
    const size_t avail = (ws_size - kCursorBytes) / ((size_t)kNumBins * 4);
    binCap = (unsigned int)(avail < (size_t)kBinCapIdeal ? avail : (size_t)kBinCapIdeal);
    binCap &= ~3u;   // keep 16B alignment for uint4 reads in K2
  }

  if (binCap >= kBinCapMin) {
    unsigned int* cursors = (unsigned int*)d_ws;
    unsigned int* recs = (unsigned int*)((char*)d_ws + kCursorBytes);
    hipMemsetAsync(d_ws, 0, kCursorBytes, stream);   // zero bin cursors each call
    const int blocks = (m + kSamplesPerBlock - 1) / kSamplesPerBlock;
    scatter_kernel<<<blocks, kThreadsK1, 0, stream>>>(ra, dec, vel, flux, recs, cursors, m, binCap);
    accum_kernel<<<kNumBins, kThreadsK2, 0, stream>>>(recs, cursors, out, binCap);
  } else {
    // workspace too small: direct-atomic fallback
    hipMemsetAsync(d_out, 0, (size_t)out_size * sizeof(float), stream);
    const int threads = 256;
    const int nThreads = (m + 3) / 4;
    const int blocks = (nThreads + threads - 1) / threads;
    cloud_raster_direct<<<blocks, threads, 0, stream>>>(ra, dec, vel, flux, out, m);
  }
}